// Round 8
// baseline (201.185 us; speedup 1.0000x reference)
//
#include <hip/hip_runtime.h>
#include <stdint.h>

#define S_LEN 4096
#define DM 1024
#define NH 16

typedef __attribute__((ext_vector_type(8))) short short8;
typedef __attribute__((ext_vector_type(4))) float float4v;
typedef __attribute__((ext_vector_type(4))) unsigned short ushort4v;

typedef __attribute__((address_space(1))) const void* as1cvp;
typedef __attribute__((address_space(3))) void* as3vp;

#define MFMA16(a, b, c) __builtin_amdgcn_mfma_f32_16x16x32_bf16((a), (b), (c), 0, 0, 0)
#define GLOAD_LDS16(g, l) \
  __builtin_amdgcn_global_load_lds((as1cvp)(g), (as3vp)(l), 16, 0, 0)

__device__ __forceinline__ unsigned short f2bf(float f) {
  unsigned u = __float_as_uint(f);
  u += 0x7fffu + ((u >> 16) & 1u);
  return (unsigned short)(u >> 16);
}

// ---------------- cast fp32 -> bf16 into workspace ----------------
__global__ __launch_bounds__(256) void cast_all(
    const float* __restrict__ q, const float* __restrict__ k, const float* __restrict__ v,
    const float* __restrict__ wq, const float* __restrict__ wk, const float* __restrict__ wv,
    const float* __restrict__ wo, unsigned short* __restrict__ dst)
{
  const float* src; size_t off; int n;
  switch (blockIdx.y) {
    case 0: src = q;  off = 0u;        n = 4194304; break;
    case 1: src = k;  off = 4194304u;  n = 4194304; break;
    case 2: src = v;  off = 8388608u;  n = 4194304; break;
    case 3: src = wq; off = 12582912u; n = 1048576; break;
    case 4: src = wk; off = 13631488u; n = 1048576; break;
    case 5: src = wv; off = 14680064u; n = 1048576; break;
    default: src = wo; off = 15728640u; n = 1048576; break;
  }
  int nv = n >> 2;
  for (int i = blockIdx.x * blockDim.x + threadIdx.x; i < nv; i += gridDim.x * blockDim.x) {
    float4v val = ((const float4v*)src)[i];
    ushort4v o;
    o.x = f2bf(val.x); o.y = f2bf(val.y); o.z = f2bf(val.z); o.w = f2bf(val.w);
    ((ushort4v*)(dst + off))[i] = o;
  }
}

// ---------------- 128x128 bt-GEMM tile (m97 structure) ----------------
// MODE 0: bf16 row-major out; MODE 1: f32 row-major out; MODE 2: bf16 TRANSPOSED out [N][4096]
template<int MODE>
__device__ __forceinline__ void gemm128(
    const unsigned short* __restrict__ A, const unsigned short* __restrict__ Bw,
    unsigned short* Cb, float* Cf, const float* __restrict__ bias, float alpha,
    unsigned short* As, unsigned short* Bs)
{
  const int K = 1024, N = 1024;
  int bm = blockIdx.x, bn = blockIdx.y;
  int t = threadIdx.x, lane = t & 63, w = t >> 6;
  int l15 = lane & 15, l4 = lane >> 4;
  int wr = w >> 1, wc = w & 1;

  float4v acc[4][4] = {};

  for (int kt = 0; kt < K / 32; ++kt) {
#pragma unroll
    for (int i = 0; i < 2; ++i) {
      int ci = i * 256 + t;
      int r = ci >> 2, cb = ci & 3;
      GLOAD_LDS16(A + (size_t)(bm * 128 + r) * K + kt * 32 + cb * 8,
                  As + (size_t)(i * 256 + w * 64) * 8);
      GLOAD_LDS16(Bw + (size_t)(bn * 128 + r) * K + kt * 32 + cb * 8,
                  Bs + (size_t)(i * 256 + w * 64) * 8);
    }
    __syncthreads();
    short8 af[4], bfr[4];
#pragma unroll
    for (int mf = 0; mf < 4; ++mf)
      af[mf] = *(const short8*)&As[(wr * 64 + mf * 16 + l15) * 32 + l4 * 8];
#pragma unroll
    for (int nf = 0; nf < 4; ++nf)
      bfr[nf] = *(const short8*)&Bs[(wc * 64 + nf * 16 + l15) * 32 + l4 * 8];
#pragma unroll
    for (int mf = 0; mf < 4; ++mf)
#pragma unroll
      for (int nf = 0; nf < 4; ++nf)
        acc[mf][nf] = MFMA16(af[mf], bfr[nf], acc[mf][nf]);
    __syncthreads();
  }

#pragma unroll
  for (int mf = 0; mf < 4; ++mf)
#pragma unroll
    for (int nf = 0; nf < 4; ++nf) {
      int col = bn * 128 + wc * 64 + nf * 16 + l15;
      float bv = bias[col];
#pragma unroll
      for (int j = 0; j < 4; ++j) {
        int row = bm * 128 + wr * 64 + mf * 16 + l4 * 4 + j;
        float val = (acc[mf][nf][j] + bv) * alpha;
        if (MODE == 1)      Cf[(size_t)row * N + col] = val;
        else if (MODE == 2) Cb[(size_t)col * S_LEN + row] = f2bf(val);  // transposed
        else                Cb[(size_t)row * N + col] = f2bf(val);
      }
    }
}

__global__ __launch_bounds__(256) void proj_qkv(
    const unsigned short* xq, const unsigned short* xk, const unsigned short* xv,
    const unsigned short* wq, const unsigned short* wk, const unsigned short* wv,
    unsigned short* Qp, unsigned short* Kp, unsigned short* Vt,
    const float* bq, const float* bk, const float* bv)
{
  __shared__ unsigned short As[128 * 32], Bs[128 * 32];
  switch (blockIdx.z) {
    case 0:  gemm128<0>(xq, wq, Qp, nullptr, bq, 0.125f, As, Bs); break; // 1/sqrt(64) folded
    case 1:  gemm128<0>(xk, wk, Kp, nullptr, bk, 1.0f,   As, Bs); break;
    default: gemm128<2>(xv, wv, Vt, nullptr, bv, 1.0f,   As, Bs); break; // V^T [1024][4096]
  }
}

__global__ __launch_bounds__(256) void proj_o(
    const unsigned short* ctx, const unsigned short* wo, float* out, const float* bo)
{
  __shared__ unsigned short As[128 * 32], Bs[128 * 32];
  gemm128<1>(ctx, wo, nullptr, out, bo, 1.0f, As, Bs);
}

// ---------------- fused flash attention ----------------
// 512 blocks (XCD-swizzled) x 256 threads (4 waves), block = (head, 128 q rows),
// wave = 32 q rows (2 row-blocks of 16: mf). KV tile 64, static unroll-2 dbuf,
// DS addresses precomputed. Swapped QK^T -> lane owns score row q = l15 (per mf).
// Online softmax with defer-max THR=8 (round-6 proven numerics path).
template<int BUF>
__device__ __forceinline__ void attn_tile(
    int kt,
    const unsigned short* kb0, const unsigned short* kb1,
    const unsigned short* vb0, const unsigned short* vb1,
    unsigned short* pw, const unsigned short* pr,
    const unsigned short* kg, const unsigned short* vg,
    unsigned short* kls, unsigned short* vls,
    const short8 (&qf)[2][2], float4v (&acc_o)[2][4],
    float (&m_run)[2], float (&l_run)[2], int l4)
{
  if (kt + 1 < 64) {   // prefetch next tile into the other buffer
    GLOAD_LDS16(kg + (size_t)(kt + 1) * (64 * DM),            kls + (1 - BUF) * 4096);
    GLOAD_LDS16(kg + (size_t)(kt + 1) * (64 * DM) + 32 * DM,  kls + (1 - BUF) * 4096 + 2048);
    GLOAD_LDS16(vg + (kt + 1) * 64,                           vls + (1 - BUF) * 4096);
    GLOAD_LDS16(vg + (kt + 1) * 64 + 32 * S_LEN,              vls + (1 - BUF) * 4096 + 2048);
  }

  // ---- QK^T (swapped: A = K rows, B = Q rows); K fragments shared across mf ----
  float4v sc[2][4];
#pragma unroll
  for (int nf = 0; nf < 4; ++nf) {
    short8 kf0 = *(const short8*)(kb0 + BUF * 4096 + nf * 1024);
    short8 kf1 = *(const short8*)(kb1 + BUF * 4096 + nf * 1024);
#pragma unroll
    for (int mf = 0; mf < 2; ++mf) {
      float4v z = {0.f, 0.f, 0.f, 0.f};
      z = MFMA16(kf0, qf[mf][0], z);
      sc[mf][nf] = MFMA16(kf1, qf[mf][1], z);
    }
  }

  // ---- online softmax per row-block (row q = mf*16 + l15), round-6 numerics ----
#pragma unroll
  for (int mf = 0; mf < 2; ++mf) {
    float mx = fmaxf(fmaxf(fmaxf(sc[mf][0][0], sc[mf][0][1]), sc[mf][0][2]), sc[mf][0][3]);
#pragma unroll
    for (int nf = 1; nf < 4; ++nf)
      mx = fmaxf(fmaxf(fmaxf(fmaxf(mx, sc[mf][nf][0]), sc[mf][nf][1]), sc[mf][nf][2]), sc[mf][nf][3]);
    mx = fmaxf(mx, __shfl_xor(mx, 16));
    mx = fmaxf(mx, __shfl_xor(mx, 32));

    if (!__all(mx <= m_run[mf] + 8.f)) {   // defer-max: rarely taken
      float mnew = fmaxf(m_run[mf], mx);
      float corr = __expf(m_run[mf] - mnew);
      m_run[mf] = mnew;
      l_run[mf] *= corr;
#pragma unroll
      for (int j = 0; j < 4; ++j) {
        float cj = __shfl(corr, l4 * 4 + j);
#pragma unroll
        for (int nf2 = 0; nf2 < 4; ++nf2) acc_o[mf][nf2][j] *= cj;
      }
    }

    float ps = 0.f;
#pragma unroll
    for (int nf = 0; nf < 4; ++nf) {
      float p0 = __expf(sc[mf][nf][0] - m_run[mf]);
      float p1 = __expf(sc[mf][nf][1] - m_run[mf]);
      float p2 = __expf(sc[mf][nf][2] - m_run[mf]);
      float p3 = __expf(sc[mf][nf][3] - m_run[mf]);
      ps += (p0 + p1) + (p2 + p3);
      unsigned lo, hi;
      asm("v_cvt_pk_bf16_f32 %0, %1, %2" : "=v"(lo) : "v"(p0), "v"(p1));
      asm("v_cvt_pk_bf16_f32 %0, %1, %2" : "=v"(hi) : "v"(p2), "v"(p3));
      uint2 u; u.x = lo; u.y = hi;
      *(uint2*)(pw + mf * 1152 + nf * 16) = u;   // ds_write_b64
    }
    ps += __shfl_xor(ps, 16);
    ps += __shfl_xor(ps, 32);
    l_run[mf] += ps;
  }

  // ---- P A-fragments (same-wave RAW through LDS) ----
  short8 pf[2][2];
#pragma unroll
  for (int mf = 0; mf < 2; ++mf)
#pragma unroll
    for (int kc = 0; kc < 2; ++kc)
      pf[mf][kc] = *(const short8*)(pr + mf * 1152 + kc * 32);

  // ---- PV; V fragments shared across mf ----
#pragma unroll
  for (int nfd = 0; nfd < 4; ++nfd) {
    short8 vf0 = *(const short8*)(vb0 + BUF * 4096 + nfd * 1024);
    short8 vf1 = *(const short8*)(vb1 + BUF * 4096 + nfd * 1024);
#pragma unroll
    for (int mf = 0; mf < 2; ++mf) {
      acc_o[mf][nfd] = MFMA16(pf[mf][0], vf0, acc_o[mf][nfd]);
      acc_o[mf][nfd] = MFMA16(pf[mf][1], vf1, acc_o[mf][nfd]);
    }
  }
  __syncthreads();   // drains prefetch (vmcnt) + all waves done with buf[BUF]
}

__global__ __launch_bounds__(256) void attn_fused(
    const unsigned short* __restrict__ Qp, const unsigned short* __restrict__ Kp,
    const unsigned short* __restrict__ Vt, unsigned short* __restrict__ ctx)
{
  __shared__ unsigned short Ks[2][64 * 64];
  __shared__ unsigned short Vts[2][64 * 64];
  __shared__ unsigned short Ps[4][32 * 72];   // 51200 B total (== round-6 footprint)

  // bijective XCD swizzle: 512 blocks, 64 consecutive wg per XCD
  int bid = blockIdx.x;
  int wg = (bid & 7) * 64 + (bid >> 3);
  int h = wg >> 5, qt = wg & 31;

  int t = threadIdx.x, lane = t & 63, w = t >> 6;
  int l15 = lane & 15, l4 = lane >> 4;

  // Q fragments (already scaled by 1/8 in projection): rows qrow0 + mf*16 + l15
  short8 qf[2][2];
  int qrow0 = qt * 128 + w * 32;
#pragma unroll
  for (int mf = 0; mf < 2; ++mf)
#pragma unroll
    for (int ks = 0; ks < 2; ++ks)
      qf[mf][ks] = *(const short8*)&Qp[(size_t)(qrow0 + mf * 16 + l15) * DM + h * 64 + ks * 32 + l4 * 8];

  float4v acc_o[2][4] = {};
  float m_run[2] = {-INFINITY, -INFINITY};
  float l_run[2] = {0.f, 0.f};

  // ---- precomputed per-lane LDS read addresses ----
  const int swz = l15 & 7;
  const unsigned short* kb0 = &Ks[0][l15 * 64 + ((l4) ^ swz) * 8];
  const unsigned short* kb1 = &Ks[0][l15 * 64 + ((4 + l4) ^ swz) * 8];
  const unsigned short* vb0 = &Vts[0][l15 * 64 + ((l4) ^ swz) * 8];
  const unsigned short* vb1 = &Vts[0][l15 * 64 + ((4 + l4) ^ swz) * 8];
  unsigned short* pw = &Ps[w][l15 * 72 + l4 * 4];
  const unsigned short* pr = &Ps[w][l15 * 72 + l4 * 8];

  // ---- staging addresses (256 threads: 2 K-loads + 2 V-loads each per tile) ----
  int sr = t >> 3, sp = t & 7;           // sr in [0,32); second half handled by +32 offsets
  int slb = sp ^ (sr & 7);               // (sr+32)&7 == sr&7, so same swizzle for both halves
  const unsigned short* kg = Kp + (size_t)sr * DM + h * 64 + slb * 8;
  const unsigned short* vg = Vt + (size_t)(h * 64 + sr) * S_LEN + slb * 8;
  unsigned short* kls = &Ks[0][t * 8];
  unsigned short* vls = &Vts[0][t * 8];

  GLOAD_LDS16(kg,                kls);
  GLOAD_LDS16(kg + 32 * DM,      kls + 2048);
  GLOAD_LDS16(vg,                vls);
  GLOAD_LDS16(vg + 32 * S_LEN,   vls + 2048);
  __syncthreads();

  for (int kt = 0; kt < 64; kt += 2) {
    attn_tile<0>(kt,     kb0, kb1, vb0, vb1, pw, pr, kg, vg, kls, vls, qf, acc_o, m_run, l_run, l4);
    attn_tile<1>(kt + 1, kb0, kb1, vb0, vb1, pw, pr, kg, vg, kls, vls, qf, acc_o, m_run, l_run, l4);
  }

  // ---- normalize + write ctx (bf16); l_run holds full row sums (all lanes, own l15) ----
#pragma unroll
  for (int mf = 0; mf < 2; ++mf) {
#pragma unroll
    for (int j = 0; j < 4; ++j) {
      float lj = __shfl(l_run[mf], l4 * 4 + j);   // lane l4*4+j has l15 == l4*4+j
      float inv = 1.0f / lj;
#pragma unroll
      for (int nfd = 0; nfd < 4; ++nfd) {
        int row = qrow0 + mf * 16 + l4 * 4 + j;
        int col = h * 64 + nfd * 16 + l15;
        ctx[(size_t)row * DM + col] = f2bf(acc_o[mf][nfd][j] * inv);
      }
    }
  }
}

// ---------------- launcher ----------------
extern "C" void kernel_launch(void* const* d_in, const int* in_sizes, int n_in,
                              void* d_out, int out_size, void* d_ws, size_t ws_size,
                              hipStream_t stream) {
  const float* q  = (const float*)d_in[0];
  const float* k  = (const float*)d_in[1];
  const float* v  = (const float*)d_in[2];
  const float* wq = (const float*)d_in[3];
  const float* bq = (const float*)d_in[4];
  const float* wk = (const float*)d_in[5];
  const float* bk = (const float*)d_in[6];
  const float* wv = (const float*)d_in[7];
  const float* bv = (const float*)d_in[8];
  const float* wo = (const float*)d_in[9];
  const float* bo = (const float*)d_in[10];

  unsigned short* ws  = (unsigned short*)d_ws;
  unsigned short* qb  = ws;                 // 4M elems (reused as ctx later)
  unsigned short* kb  = ws + 4194304u;
  unsigned short* vb  = ws + 8388608u;
  unsigned short* wqb = ws + 12582912u;
  unsigned short* wkb = ws + 13631488u;
  unsigned short* wvb = ws + 14680064u;
  unsigned short* wob = ws + 15728640u;
  unsigned short* Qp  = ws + 16777216u;
  unsigned short* Kp  = ws + 20971520u;
  unsigned short* Vt  = ws + 25165824u;     // V^T [1024][4096]
  unsigned short* ctx = qb;                 // safe reuse: qb consumed by proj_qkv before attn
  float* out = (float*)d_out;

  cast_all<<<dim3(1024, 7), 256, 0, stream>>>(q, k, v, wq, wk, wv, wo, ws);
  proj_qkv<<<dim3(32, 8, 3), 256, 0, stream>>>(qb, kb, vb, wqb, wkb, wvb, Qp, Kp, Vt, bq, bk, bv);
  attn_fused<<<dim3(512), 256, 0, stream>>>(Qp, Kp, Vt, ctx);
  proj_o<<<dim3(32, 8), 256, 0, stream>>>(ctx, wob, out, bo);
}

// Round 9
// 198.401 us; speedup vs baseline: 1.0140x; 1.0140x over previous
//
#include <hip/hip_runtime.h>
#include <stdint.h>

#define S_LEN 4096
#define DM 1024
#define NH 16

typedef __attribute__((ext_vector_type(8))) short short8;
typedef __attribute__((ext_vector_type(4))) float float4v;
typedef __attribute__((ext_vector_type(4))) unsigned short ushort4v;

typedef __attribute__((address_space(1))) const void* as1cvp;
typedef __attribute__((address_space(3))) void* as3vp;

#define MFMA16(a, b, c) __builtin_amdgcn_mfma_f32_16x16x32_bf16((a), (b), (c), 0, 0, 0)
#define GLOAD_LDS16(g, l) \
  __builtin_amdgcn_global_load_lds((as1cvp)(g), (as3vp)(l), 16, 0, 0)

__device__ __forceinline__ unsigned short f2bf(float f) {
  unsigned u = __float_as_uint(f);
  u += 0x7fffu + ((u >> 16) & 1u);
  return (unsigned short)(u >> 16);
}

// ---------------- cast fp32 -> bf16 into workspace ----------------
__global__ __launch_bounds__(256) void cast_all(
    const float* __restrict__ q, const float* __restrict__ k, const float* __restrict__ v,
    const float* __restrict__ wq, const float* __restrict__ wk, const float* __restrict__ wv,
    const float* __restrict__ wo, unsigned short* __restrict__ dst)
{
  const float* src; size_t off; int n;
  switch (blockIdx.y) {
    case 0: src = q;  off = 0u;        n = 4194304; break;
    case 1: src = k;  off = 4194304u;  n = 4194304; break;
    case 2: src = v;  off = 8388608u;  n = 4194304; break;
    case 3: src = wq; off = 12582912u; n = 1048576; break;
    case 4: src = wk; off = 13631488u; n = 1048576; break;
    case 5: src = wv; off = 14680064u; n = 1048576; break;
    default: src = wo; off = 15728640u; n = 1048576; break;
  }
  int nv = n >> 2;
  for (int i = blockIdx.x * blockDim.x + threadIdx.x; i < nv; i += gridDim.x * blockDim.x) {
    float4v val = ((const float4v*)src)[i];
    ushort4v o;
    o.x = f2bf(val.x); o.y = f2bf(val.y); o.z = f2bf(val.z); o.w = f2bf(val.w);
    ((ushort4v*)(dst + off))[i] = o;
  }
}

// ---------------- 128x128 bt-GEMM tile (m97 structure) ----------------
// MODE 0: bf16 row-major out; MODE 1: f32 row-major out; MODE 2: bf16 TRANSPOSED out [N][4096]
template<int MODE>
__device__ __forceinline__ void gemm128(
    const unsigned short* __restrict__ A, const unsigned short* __restrict__ Bw,
    unsigned short* Cb, float* Cf, const float* __restrict__ bias, float alpha,
    unsigned short* As, unsigned short* Bs)
{
  const int K = 1024, N = 1024;
  int bm = blockIdx.x, bn = blockIdx.y;
  int t = threadIdx.x, lane = t & 63, w = t >> 6;
  int l15 = lane & 15, l4 = lane >> 4;
  int wr = w >> 1, wc = w & 1;

  float4v acc[4][4] = {};

  for (int kt = 0; kt < K / 32; ++kt) {
#pragma unroll
    for (int i = 0; i < 2; ++i) {
      int ci = i * 256 + t;
      int r = ci >> 2, cb = ci & 3;
      GLOAD_LDS16(A + (size_t)(bm * 128 + r) * K + kt * 32 + cb * 8,
                  As + (size_t)(i * 256 + w * 64) * 8);
      GLOAD_LDS16(Bw + (size_t)(bn * 128 + r) * K + kt * 32 + cb * 8,
                  Bs + (size_t)(i * 256 + w * 64) * 8);
    }
    __syncthreads();
    short8 af[4], bfr[4];
#pragma unroll
    for (int mf = 0; mf < 4; ++mf)
      af[mf] = *(const short8*)&As[(wr * 64 + mf * 16 + l15) * 32 + l4 * 8];
#pragma unroll
    for (int nf = 0; nf < 4; ++nf)
      bfr[nf] = *(const short8*)&Bs[(wc * 64 + nf * 16 + l15) * 32 + l4 * 8];
#pragma unroll
    for (int mf = 0; mf < 4; ++mf)
#pragma unroll
      for (int nf = 0; nf < 4; ++nf)
        acc[mf][nf] = MFMA16(af[mf], bfr[nf], acc[mf][nf]);
    __syncthreads();
  }

#pragma unroll
  for (int mf = 0; mf < 4; ++mf)
#pragma unroll
    for (int nf = 0; nf < 4; ++nf) {
      int col = bn * 128 + wc * 64 + nf * 16 + l15;
      float bv = bias[col];
#pragma unroll
      for (int j = 0; j < 4; ++j) {
        int row = bm * 128 + wr * 64 + mf * 16 + l4 * 4 + j;
        float val = (acc[mf][nf][j] + bv) * alpha;
        if (MODE == 1)      Cf[(size_t)row * N + col] = val;
        else if (MODE == 2) Cb[(size_t)col * S_LEN + row] = f2bf(val);  // transposed
        else                Cb[(size_t)row * N + col] = f2bf(val);
      }
    }
}

__global__ __launch_bounds__(256) void proj_qkv(
    const unsigned short* xq, const unsigned short* xk, const unsigned short* xv,
    const unsigned short* wq, const unsigned short* wk, const unsigned short* wv,
    unsigned short* Qp, unsigned short* Kp, unsigned short* Vt,
    const float* bq, const float* bk, const float* bv)
{
  __shared__ unsigned short As[128 * 32], Bs[128 * 32];
  switch (blockIdx.z) {
    case 0:  gemm128<0>(xq, wq, Qp, nullptr, bq, 0.125f, As, Bs); break; // 1/sqrt(64) folded
    case 1:  gemm128<0>(xk, wk, Kp, nullptr, bk, 1.0f,   As, Bs); break;
    default: gemm128<2>(xv, wv, Vt, nullptr, bv, 1.0f,   As, Bs); break; // V^T [1024][4096]
  }
}

__global__ __launch_bounds__(256) void proj_o(
    const unsigned short* ctx, const unsigned short* wo, float* out, const float* bo)
{
  __shared__ unsigned short As[128 * 32], Bs[128 * 32];
  gemm128<1>(ctx, wo, nullptr, out, bo, 1.0f, As, Bs);
}

// ---------------- fused flash attention ----------------
// 512 blocks (XCD-swizzled) x 256 threads (4 waves), wave = 32 q rows (mf=2).
// RING-3 LDS + 2-deep tile pipeline: step t executes QK^T(t+1) in the same
// barrier-free region as softmax(t)+P+PV(t), so MFMA/DS of t+1 hide the
// softmax VALU chain and P-roundtrip lgkm waits of t. stage(t+3) issues after
// the barrier into the buffer whose V(t) was just consumed.
#define STAGE_T(BUFI, ktv) do {                                              \
    GLOAD_LDS16(kg + (size_t)(ktv) * (64 * DM),               kls + (BUFI) * 4096);        \
    GLOAD_LDS16(kg + (size_t)(ktv) * (64 * DM) + 32 * DM,     kls + (BUFI) * 4096 + 2048); \
    GLOAD_LDS16(vg + (size_t)(ktv) * 64,                      vls + (BUFI) * 4096);        \
    GLOAD_LDS16(vg + (size_t)(ktv) * 64 + (size_t)32 * S_LEN, vls + (BUFI) * 4096 + 2048); \
  } while (0)

template<int BUFN>
__device__ __forceinline__ void qkt_into(
    float4v (&scN)[2][4],
    const unsigned short* kb0, const unsigned short* kb1,
    const short8 (&qf)[2][2])
{
#pragma unroll
  for (int nf = 0; nf < 4; ++nf) {
    short8 kf0 = *(const short8*)(kb0 + BUFN * 4096 + nf * 1024);
    short8 kf1 = *(const short8*)(kb1 + BUFN * 4096 + nf * 1024);
#pragma unroll
    for (int mf = 0; mf < 2; ++mf) {
      float4v z = {0.f, 0.f, 0.f, 0.f};
      z = MFMA16(kf0, qf[mf][0], z);
      scN[mf][nf] = MFMA16(kf1, qf[mf][1], z);
    }
  }
}

template<int BC>
__device__ __forceinline__ void softmax_pv(
    float4v (&sc)[2][4],
    const unsigned short* vb0, const unsigned short* vb1,
    unsigned short* pw, const unsigned short* pr,
    float4v (&acc_o)[2][4], float (&m_run)[2], float (&l_run)[2], int l4)
{
#pragma unroll
  for (int mf = 0; mf < 2; ++mf) {
    float mx = fmaxf(fmaxf(fmaxf(sc[mf][0][0], sc[mf][0][1]), sc[mf][0][2]), sc[mf][0][3]);
#pragma unroll
    for (int nf = 1; nf < 4; ++nf)
      mx = fmaxf(fmaxf(fmaxf(fmaxf(mx, sc[mf][nf][0]), sc[mf][nf][1]), sc[mf][nf][2]), sc[mf][nf][3]);
    mx = fmaxf(mx, __shfl_xor(mx, 16));
    mx = fmaxf(mx, __shfl_xor(mx, 32));

    if (!__all(mx <= m_run[mf] + 8.f)) {   // defer-max: rarely taken
      float mnew = fmaxf(m_run[mf], mx);
      float corr = __expf(m_run[mf] - mnew);
      m_run[mf] = mnew;
      l_run[mf] *= corr;
#pragma unroll
      for (int j = 0; j < 4; ++j) {
        float cj = __shfl(corr, l4 * 4 + j);
#pragma unroll
        for (int nf2 = 0; nf2 < 4; ++nf2) acc_o[mf][nf2][j] *= cj;
      }
    }

    float ps = 0.f;
#pragma unroll
    for (int nf = 0; nf < 4; ++nf) {
      float p0 = __expf(sc[mf][nf][0] - m_run[mf]);
      float p1 = __expf(sc[mf][nf][1] - m_run[mf]);
      float p2 = __expf(sc[mf][nf][2] - m_run[mf]);
      float p3 = __expf(sc[mf][nf][3] - m_run[mf]);
      ps += (p0 + p1) + (p2 + p3);
      unsigned lo, hi;
      asm("v_cvt_pk_bf16_f32 %0, %1, %2" : "=v"(lo) : "v"(p0), "v"(p1));
      asm("v_cvt_pk_bf16_f32 %0, %1, %2" : "=v"(hi) : "v"(p2), "v"(p3));
      uint2 u; u.x = lo; u.y = hi;
      *(uint2*)(pw + mf * 1152 + nf * 16) = u;   // ds_write_b64
    }
    ps += __shfl_xor(ps, 16);
    ps += __shfl_xor(ps, 32);
    l_run[mf] += ps;
  }

  // P A-fragments (same-wave RAW through LDS)
  short8 pf[2][2];
#pragma unroll
  for (int mf = 0; mf < 2; ++mf)
#pragma unroll
    for (int kc = 0; kc < 2; ++kc)
      pf[mf][kc] = *(const short8*)(pr + mf * 1152 + kc * 32);

  // PV; V fragments shared across mf
#pragma unroll
  for (int nfd = 0; nfd < 4; ++nfd) {
    short8 vf0 = *(const short8*)(vb0 + BC * 4096 + nfd * 1024);
    short8 vf1 = *(const short8*)(vb1 + BC * 4096 + nfd * 1024);
#pragma unroll
    for (int mf = 0; mf < 2; ++mf) {
      acc_o[mf][nfd] = MFMA16(pf[mf][0], vf0, acc_o[mf][nfd]);
      acc_o[mf][nfd] = MFMA16(pf[mf][1], vf1, acc_o[mf][nfd]);
    }
  }
}

template<int BC>
__device__ __forceinline__ void attn_step(
    int t, bool do_stage,
    float4v (&scC)[2][4], float4v (&scN)[2][4],
    const unsigned short* kb0, const unsigned short* kb1,
    const unsigned short* vb0, const unsigned short* vb1,
    unsigned short* pw, const unsigned short* pr,
    const unsigned short* kg, const unsigned short* vg,
    unsigned short* kls, unsigned short* vls,
    const short8 (&qf)[2][2], float4v (&acc_o)[2][4],
    float (&m_run)[2], float (&l_run)[2], int l4)
{
  constexpr int BN = (BC + 1) % 3;
  qkt_into<BN>(scN, kb0, kb1, qf);                       // tile t+1 (independent)
  softmax_pv<BC>(scC, vb0, vb1, pw, pr, acc_o, m_run, l_run, l4);  // tile t
  __syncthreads();                                       // drains stage(t+2); all done with buf BC
  if (do_stage) STAGE_T(BC, t + 3);                      // reuse buf BC for tile t+3
}

__global__ __launch_bounds__(256) void attn_fused(
    const unsigned short* __restrict__ Qp, const unsigned short* __restrict__ Kp,
    const unsigned short* __restrict__ Vt, unsigned short* __restrict__ ctx)
{
  __shared__ unsigned short Ks[3][64 * 64];
  __shared__ unsigned short Vts[3][64 * 64];
  __shared__ unsigned short Ps[4][32 * 72];

  // bijective XCD swizzle: 512 blocks, 64 consecutive wg per XCD
  int bid = blockIdx.x;
  int wg = (bid & 7) * 64 + (bid >> 3);
  int h = wg >> 5, qt = wg & 31;

  int t = threadIdx.x, lane = t & 63, w = t >> 6;
  int l15 = lane & 15, l4 = lane >> 4;

  // Q fragments (already scaled by 1/8 in projection): rows qrow0 + mf*16 + l15
  short8 qf[2][2];
  int qrow0 = qt * 128 + w * 32;
#pragma unroll
  for (int mf = 0; mf < 2; ++mf)
#pragma unroll
    for (int ks = 0; ks < 2; ++ks)
      qf[mf][ks] = *(const short8*)&Qp[(size_t)(qrow0 + mf * 16 + l15) * DM + h * 64 + ks * 32 + l4 * 8];

  float4v acc_o[2][4] = {};
  float m_run[2] = {-INFINITY, -INFINITY};
  float l_run[2] = {0.f, 0.f};

  // precomputed per-lane LDS read addresses (buffer 0 base; +BUF*4096 immediates)
  const int swz = l15 & 7;
  const unsigned short* kb0 = &Ks[0][l15 * 64 + ((l4) ^ swz) * 8];
  const unsigned short* kb1 = &Ks[0][l15 * 64 + ((4 + l4) ^ swz) * 8];
  const unsigned short* vb0 = &Vts[0][l15 * 64 + ((l4) ^ swz) * 8];
  const unsigned short* vb1 = &Vts[0][l15 * 64 + ((4 + l4) ^ swz) * 8];
  unsigned short* pw = &Ps[w][l15 * 72 + l4 * 4];
  const unsigned short* pr = &Ps[w][l15 * 72 + l4 * 8];

  // staging addresses (256 threads: 2 K-loads + 2 V-loads each per tile)
  int sr = t >> 3, sp = t & 7;
  int slb = sp ^ (sr & 7);
  const unsigned short* kg = Kp + (size_t)sr * DM + h * 64 + slb * 8;
  const unsigned short* vg = Vt + (size_t)(h * 64 + sr) * S_LEN + slb * 8;
  unsigned short* kls = &Ks[0][t * 8];
  unsigned short* vls = &Vts[0][t * 8];

  float4v scA[2][4], scB[2][4];

  // ---- pipeline prologue ----
  STAGE_T(0, 0);
  __syncthreads();            // buf0 valid
  STAGE_T(1, 1);              // in flight
  qkt_into<0>(scA, kb0, kb1, qf);   // sc(0)
  __syncthreads();            // drains stage(1) -> buf1 valid
  STAGE_T(2, 2);              // in flight

  // ---- 63 pipelined steps (tile t finished; tile t+1's scores computed) ----
  for (int kt = 0; kt < 60; kt += 6) {
    attn_step<0>(kt,     true, scA, scB, kb0, kb1, vb0, vb1, pw, pr, kg, vg, kls, vls, qf, acc_o, m_run, l_run, l4);
    attn_step<1>(kt + 1, true, scB, scA, kb0, kb1, vb0, vb1, pw, pr, kg, vg, kls, vls, qf, acc_o, m_run, l_run, l4);
    attn_step<2>(kt + 2, true, scA, scB, kb0, kb1, vb0, vb1, pw, pr, kg, vg, kls, vls, qf, acc_o, m_run, l_run, l4);
    attn_step<0>(kt + 3, true, scB, scA, kb0, kb1, vb0, vb1, pw, pr, kg, vg, kls, vls, qf, acc_o, m_run, l_run, l4);
    attn_step<1>(kt + 4, true, scA, scB, kb0, kb1, vb0, vb1, pw, pr, kg, vg, kls, vls, qf, acc_o, m_run, l_run, l4);
    attn_step<2>(kt + 5, true, scB, scA, kb0, kb1, vb0, vb1, pw, pr, kg, vg, kls, vls, qf, acc_o, m_run, l_run, l4);
  }
  attn_step<0>(60, true,  scA, scB, kb0, kb1, vb0, vb1, pw, pr, kg, vg, kls, vls, qf, acc_o, m_run, l_run, l4);
  attn_step<1>(61, false, scB, scA, kb0, kb1, vb0, vb1, pw, pr, kg, vg, kls, vls, qf, acc_o, m_run, l_run, l4);
  attn_step<2>(62, false, scA, scB, kb0, kb1, vb0, vb1, pw, pr, kg, vg, kls, vls, qf, acc_o, m_run, l_run, l4);
  // tile 63 (63 % 3 == 0 -> V in buf 0); scores in scB
  softmax_pv<0>(scB, vb0, vb1, pw, pr, acc_o, m_run, l_run, l4);

  // ---- normalize + write ctx (bf16) ----
#pragma unroll
  for (int mf = 0; mf < 2; ++mf) {
#pragma unroll
    for (int j = 0; j < 4; ++j) {
      float lj = __shfl(l_run[mf], l4 * 4 + j);   // lane l4*4+j has l15 == l4*4+j
      float inv = 1.0f / lj;
#pragma unroll
      for (int nfd = 0; nfd < 4; ++nfd) {
        int row = qrow0 + mf * 16 + l4 * 4 + j;
        int col = h * 64 + nfd * 16 + l15;
        ctx[(size_t)row * DM + col] = f2bf(acc_o[mf][nfd][j] * inv);
      }
    }
  }
}

// ---------------- launcher ----------------
extern "C" void kernel_launch(void* const* d_in, const int* in_sizes, int n_in,
                              void* d_out, int out_size, void* d_ws, size_t ws_size,
                              hipStream_t stream) {
  const float* q  = (const float*)d_in[0];
  const float* k  = (const float*)d_in[1];
  const float* v  = (const float*)d_in[2];
  const float* wq = (const float*)d_in[3];
  const float* bq = (const float*)d_in[4];
  const float* wk = (const float*)d_in[5];
  const float* bk = (const float*)d_in[6];
  const float* wv = (const float*)d_in[7];
  const float* bv = (const float*)d_in[8];
  const float* wo = (const float*)d_in[9];
  const float* bo = (const float*)d_in[10];

  unsigned short* ws  = (unsigned short*)d_ws;
  unsigned short* qb  = ws;                 // 4M elems (reused as ctx later)
  unsigned short* kb  = ws + 4194304u;
  unsigned short* vb  = ws + 8388608u;
  unsigned short* wqb = ws + 12582912u;
  unsigned short* wkb = ws + 13631488u;
  unsigned short* wvb = ws + 14680064u;
  unsigned short* wob = ws + 15728640u;
  unsigned short* Qp  = ws + 16777216u;
  unsigned short* Kp  = ws + 20971520u;
  unsigned short* Vt  = ws + 25165824u;     // V^T [1024][4096]
  unsigned short* ctx = qb;                 // safe reuse: qb consumed by proj_qkv before attn
  float* out = (float*)d_out;

  cast_all<<<dim3(1024, 7), 256, 0, stream>>>(q, k, v, wq, wk, wv, wo, ws);
  proj_qkv<<<dim3(32, 8, 3), 256, 0, stream>>>(qb, kb, vb, wqb, wkb, wvb, Qp, Kp, Vt, bq, bk, bv);
  attn_fused<<<dim3(512), 256, 0, stream>>>(Qp, Kp, Vt, ctx);
  proj_o<<<dim3(32, 8), 256, 0, stream>>>(ctx, wob, out, bo);
}

// Round 10
// 195.430 us; speedup vs baseline: 1.0294x; 1.0152x over previous
//
#include <hip/hip_runtime.h>
#include <stdint.h>

#define S_LEN 4096
#define DM 1024
#define NH 16

typedef __attribute__((ext_vector_type(8))) short short8;
typedef __attribute__((ext_vector_type(4))) short short4v;
typedef __attribute__((ext_vector_type(4))) float float4v;
typedef __attribute__((ext_vector_type(4))) unsigned short ushort4v;

typedef __attribute__((address_space(1))) const void* as1cvp;
typedef __attribute__((address_space(3))) void* as3vp;

#define MFMA16(a, b, c) __builtin_amdgcn_mfma_f32_16x16x32_bf16((a), (b), (c), 0, 0, 0)
#define MFMA16K16(a, b, c) __builtin_amdgcn_mfma_f32_16x16x16bf16_1k((a), (b), (c), 0, 0, 0)
#define GLOAD_LDS16(g, l) \
  __builtin_amdgcn_global_load_lds((as1cvp)(g), (as3vp)(l), 16, 0, 0)

__device__ __forceinline__ unsigned short f2bf(float f) {
  unsigned u = __float_as_uint(f);
  u += 0x7fffu + ((u >> 16) & 1u);
  return (unsigned short)(u >> 16);
}

__device__ __forceinline__ float exp2_hw(float x) {
  float r;
  asm("v_exp_f32 %0, %1" : "=v"(r) : "v"(x));
  return r;
}

// ---------------- cast fp32 -> bf16 into workspace ----------------
__global__ __launch_bounds__(256) void cast_all(
    const float* __restrict__ q, const float* __restrict__ k, const float* __restrict__ v,
    const float* __restrict__ wq, const float* __restrict__ wk, const float* __restrict__ wv,
    const float* __restrict__ wo, unsigned short* __restrict__ dst)
{
  const float* src; size_t off; int n;
  switch (blockIdx.y) {
    case 0: src = q;  off = 0u;        n = 4194304; break;
    case 1: src = k;  off = 4194304u;  n = 4194304; break;
    case 2: src = v;  off = 8388608u;  n = 4194304; break;
    case 3: src = wq; off = 12582912u; n = 1048576; break;
    case 4: src = wk; off = 13631488u; n = 1048576; break;
    case 5: src = wv; off = 14680064u; n = 1048576; break;
    default: src = wo; off = 15728640u; n = 1048576; break;
  }
  int nv = n >> 2;
  for (int i = blockIdx.x * blockDim.x + threadIdx.x; i < nv; i += gridDim.x * blockDim.x) {
    float4v val = ((const float4v*)src)[i];
    ushort4v o;
    o.x = f2bf(val.x); o.y = f2bf(val.y); o.z = f2bf(val.z); o.w = f2bf(val.w);
    ((ushort4v*)(dst + off))[i] = o;
  }
}

// ---------------- 128x128 bt-GEMM tile (m97 structure) ----------------
// MODE 0: bf16 row-major out; MODE 1: f32 row-major out; MODE 2: bf16 TRANSPOSED out [N][4096]
template<int MODE>
__device__ __forceinline__ void gemm128(
    const unsigned short* __restrict__ A, const unsigned short* __restrict__ Bw,
    unsigned short* Cb, float* Cf, const float* __restrict__ bias, float alpha,
    unsigned short* As, unsigned short* Bs)
{
  const int K = 1024, N = 1024;
  int bm = blockIdx.x, bn = blockIdx.y;
  int t = threadIdx.x, lane = t & 63, w = t >> 6;
  int l15 = lane & 15, l4 = lane >> 4;
  int wr = w >> 1, wc = w & 1;

  float4v acc[4][4] = {};

  for (int kt = 0; kt < K / 32; ++kt) {
#pragma unroll
    for (int i = 0; i < 2; ++i) {
      int ci = i * 256 + t;
      int r = ci >> 2, cb = ci & 3;
      GLOAD_LDS16(A + (size_t)(bm * 128 + r) * K + kt * 32 + cb * 8,
                  As + (size_t)(i * 256 + w * 64) * 8);
      GLOAD_LDS16(Bw + (size_t)(bn * 128 + r) * K + kt * 32 + cb * 8,
                  Bs + (size_t)(i * 256 + w * 64) * 8);
    }
    __syncthreads();
    short8 af[4], bfr[4];
#pragma unroll
    for (int mf = 0; mf < 4; ++mf)
      af[mf] = *(const short8*)&As[(wr * 64 + mf * 16 + l15) * 32 + l4 * 8];
#pragma unroll
    for (int nf = 0; nf < 4; ++nf)
      bfr[nf] = *(const short8*)&Bs[(wc * 64 + nf * 16 + l15) * 32 + l4 * 8];
#pragma unroll
    for (int mf = 0; mf < 4; ++mf)
#pragma unroll
      for (int nf = 0; nf < 4; ++nf)
        acc[mf][nf] = MFMA16(af[mf], bfr[nf], acc[mf][nf]);
    __syncthreads();
  }

#pragma unroll
  for (int mf = 0; mf < 4; ++mf)
#pragma unroll
    for (int nf = 0; nf < 4; ++nf) {
      int col = bn * 128 + wc * 64 + nf * 16 + l15;
      float bv = bias[col];
#pragma unroll
      for (int j = 0; j < 4; ++j) {
        int row = bm * 128 + wr * 64 + mf * 16 + l4 * 4 + j;
        float val = (acc[mf][nf][j] + bv) * alpha;
        if (MODE == 1)      Cf[(size_t)row * N + col] = val;
        else if (MODE == 2) Cb[(size_t)col * S_LEN + row] = f2bf(val);  // transposed
        else                Cb[(size_t)row * N + col] = f2bf(val);
      }
    }
}

__global__ __launch_bounds__(256) void proj_qkv(
    const unsigned short* xq, const unsigned short* xk, const unsigned short* xv,
    const unsigned short* wq, const unsigned short* wk, const unsigned short* wv,
    unsigned short* Qp, unsigned short* Kp, unsigned short* Vt,
    const float* bq, const float* bk, const float* bv)
{
  __shared__ unsigned short As[128 * 32], Bs[128 * 32];
  switch (blockIdx.z) {
    // Q scale = (1/sqrt(64)) * log2(e): softmax runs in exp2 domain
    case 0:  gemm128<0>(xq, wq, Qp, nullptr, bq, 0.1803368867f, As, Bs); break;
    case 1:  gemm128<0>(xk, wk, Kp, nullptr, bk, 1.0f,          As, Bs); break;
    default: gemm128<2>(xv, wv, Vt, nullptr, bv, 1.0f,          As, Bs); break; // V^T [1024][4096]
  }
}

__global__ __launch_bounds__(256) void proj_o(
    const unsigned short* ctx, const unsigned short* wo, float* out, const float* bo)
{
  __shared__ unsigned short As[128 * 32], Bs[128 * 32];
  gemm128<1>(ctx, wo, nullptr, out, bo, 1.0f, As, Bs);
}

// ---------------- fused flash attention ----------------
// 512 blocks (XCD-swizzled) x 512 threads (8 waves), wave = 16 q rows.
// Swapped QK^T (sc[nf][reg] = S[q=l15][k=nf*16+l4*4+reg], exp2 domain).
// PV uses mfma 16x16x16: its A-fragment layout (A[row=l15][k=l4*4+e]) EQUALS the
// QK^T C/D layout, so the cvt_pk-converted P lives directly in registers --
// no P LDS round-trip. V^T B-fragments are 8B ds_read_b64 per (k-block, d-block).
template<int BUF>
__device__ __forceinline__ void attn_tile(
    int kt,
    const unsigned short* kb0, const unsigned short* kb1,
    const int (&vAe)[4], const unsigned short* vbase,
    const unsigned short* kg, const unsigned short* vg,
    unsigned short* kls, unsigned short* vls,
    const short8 (&qf)[2], float4v (&acc_o)[4], float& m_run, float& l_run,
    int l4)
{
  if (kt + 1 < 64) {   // prefetch next tile into the other buffer
    GLOAD_LDS16(kg + (size_t)(kt + 1) * (64 * DM), kls + (1 - BUF) * 4096);
    GLOAD_LDS16(vg + (kt + 1) * 64, vls + (1 - BUF) * 4096);
  }

  // ---- QK^T (swapped: A = K rows, B = Q rows) ----
  float4v sc[4];
#pragma unroll
  for (int nf = 0; nf < 4; ++nf) {
    short8 kf0 = *(const short8*)(kb0 + BUF * 4096 + nf * 1024);
    short8 kf1 = *(const short8*)(kb1 + BUF * 4096 + nf * 1024);
    float4v z = {0.f, 0.f, 0.f, 0.f};
    z = MFMA16(kf0, qf[0], z);
    sc[nf] = MFMA16(kf1, qf[1], z);
  }

  // ---- row max (q = l15), exp2 domain ----
  float mx = fmaxf(fmaxf(fmaxf(sc[0][0], sc[0][1]), sc[0][2]), sc[0][3]);
#pragma unroll
  for (int nf = 1; nf < 4; ++nf)
    mx = fmaxf(fmaxf(fmaxf(fmaxf(mx, sc[nf][0]), sc[nf][1]), sc[nf][2]), sc[nf][3]);
  mx = fmaxf(mx, __shfl_xor(mx, 16));
  mx = fmaxf(mx, __shfl_xor(mx, 32));

  if (!__all(mx <= m_run + 11.5f)) {   // defer-max (11.5 = 8 nats in log2 units)
    float mnew = fmaxf(m_run, mx);
    float corr = exp2_hw(m_run - mnew);
    m_run = mnew;
    l_run *= corr;
#pragma unroll
    for (int j = 0; j < 4; ++j) {
      float cj = __shfl(corr, l4 * 4 + j);
#pragma unroll
      for (int nf2 = 0; nf2 < 4; ++nf2) acc_o[nf2][j] *= cj;
    }
  }

  // ---- exp2 + packed bf16: pa[nf] IS the 16x16x16 A-fragment (k = l4*4+e) ----
  float ps = 0.f;
  short4v pa[4];
#pragma unroll
  for (int nf = 0; nf < 4; ++nf) {
    float p0 = exp2_hw(sc[nf][0] - m_run);
    float p1 = exp2_hw(sc[nf][1] - m_run);
    float p2 = exp2_hw(sc[nf][2] - m_run);
    float p3 = exp2_hw(sc[nf][3] - m_run);
    ps += (p0 + p1) + (p2 + p3);
    unsigned lo, hi;
    asm("v_cvt_pk_bf16_f32 %0, %1, %2" : "=v"(lo) : "v"(p0), "v"(p1));
    asm("v_cvt_pk_bf16_f32 %0, %1, %2" : "=v"(hi) : "v"(p2), "v"(p3));
    union { unsigned u[2]; short4v s; } pk;
    pk.u[0] = lo; pk.u[1] = hi;
    pa[nf] = pk.s;
  }
  ps += __shfl_xor(ps, 16);
  ps += __shfl_xor(ps, 32);
  l_run += ps;

  // ---- PV: 16 x mfma 16x16x16, V^T b64 fragments (swizzle folded into vAe) ----
#pragma unroll
  for (int nfd = 0; nfd < 4; ++nfd)
#pragma unroll
    for (int nf = 0; nf < 4; ++nf) {
      short4v vf = *(const short4v*)(vbase + vAe[nf] + BUF * 4096 + nfd * 1024);
      acc_o[nfd] = MFMA16K16(pa[nf], vf, acc_o[nfd]);
    }

  __syncthreads();   // drains prefetch (vmcnt) + all waves done with buf[BUF]
}

__global__ __launch_bounds__(512) void attn_fused(
    const unsigned short* __restrict__ Qp, const unsigned short* __restrict__ Kp,
    const unsigned short* __restrict__ Vt, unsigned short* __restrict__ ctx)
{
  __shared__ unsigned short Ks[2][64 * 64];
  __shared__ unsigned short Vts[2][64 * 64];

  // bijective XCD swizzle: 512 blocks, 64 consecutive wg per XCD
  int bid = blockIdx.x;
  int wg = (bid & 7) * 64 + (bid >> 3);
  int h = wg >> 5, qt = wg & 31;

  int t = threadIdx.x, lane = t & 63, w = t >> 6;
  int l15 = lane & 15, l4 = lane >> 4;

  // Q fragments (pre-scaled by 0.125*log2e in projection)
  short8 qf[2];
  int qrow0 = qt * 128 + w * 16;
#pragma unroll
  for (int ks = 0; ks < 2; ++ks)
    qf[ks] = *(const short8*)&Qp[(size_t)(qrow0 + l15) * DM + h * 64 + ks * 32 + l4 * 8];

  float4v acc_o[4] = {};
  float m_run = -INFINITY, l_run = 0.f;

  // ---- precomputed per-lane LDS read addresses ----
  const int swz = l15 & 7;
  const unsigned short* kb0 = &Ks[0][l15 * 64 + ((l4) ^ swz) * 8];
  const unsigned short* kb1 = &Ks[0][l15 * 64 + ((4 + l4) ^ swz) * 8];
  // V b64 fragment element offsets: row l15 (+nfd*16 via imm), 16B-block (2nf+(l4>>1))^swz, half l4&1
  int vAe[4];
#pragma unroll
  for (int nf = 0; nf < 4; ++nf)
    vAe[nf] = l15 * 64 + (((2 * nf + (l4 >> 1)) ^ swz) * 8) + (l4 & 1) * 4;
  const unsigned short* vbase = &Vts[0][0];

  // ---- staging addresses (512 threads: 1 K-load + 1 V-load each per tile) ----
  int sr = t >> 3, sp = t & 7;
  int slb = sp ^ (sr & 7);
  const unsigned short* kg = Kp + (size_t)sr * DM + h * 64 + slb * 8;
  const unsigned short* vg = Vt + (size_t)(h * 64 + sr) * S_LEN + slb * 8;
  unsigned short* kls = &Ks[0][t * 8];
  unsigned short* vls = &Vts[0][t * 8];

  GLOAD_LDS16(kg, kls);
  GLOAD_LDS16(vg, vls);
  __syncthreads();

  for (int kt = 0; kt < 64; kt += 2) {
    attn_tile<0>(kt,     kb0, kb1, vAe, vbase, kg, vg, kls, vls, qf, acc_o, m_run, l_run, l4);
    attn_tile<1>(kt + 1, kb0, kb1, vAe, vbase, kg, vg, kls, vls, qf, acc_o, m_run, l_run, l4);
  }

  // ---- normalize + write ctx (bf16); l_run for row q lives in lane q ----
#pragma unroll
  for (int j = 0; j < 4; ++j) {
    float lj = __shfl(l_run, l4 * 4 + j);
    float inv = 1.0f / lj;
#pragma unroll
    for (int nfd = 0; nfd < 4; ++nfd) {
      int row = qrow0 + l4 * 4 + j;
      int col = h * 64 + nfd * 16 + l15;
      ctx[(size_t)row * DM + col] = f2bf(acc_o[nfd][j] * inv);
    }
  }
}

// ---------------- launcher ----------------
extern "C" void kernel_launch(void* const* d_in, const int* in_sizes, int n_in,
                              void* d_out, int out_size, void* d_ws, size_t ws_size,
                              hipStream_t stream) {
  const float* q  = (const float*)d_in[0];
  const float* k  = (const float*)d_in[1];
  const float* v  = (const float*)d_in[2];
  const float* wq = (const float*)d_in[3];
  const float* bq = (const float*)d_in[4];
  const float* wk = (const float*)d_in[5];
  const float* bk = (const float*)d_in[6];
  const float* wv = (const float*)d_in[7];
  const float* bv = (const float*)d_in[8];
  const float* wo = (const float*)d_in[9];
  const float* bo = (const float*)d_in[10];

  unsigned short* ws  = (unsigned short*)d_ws;
  unsigned short* qb  = ws;                 // 4M elems (reused as ctx later)
  unsigned short* kb  = ws + 4194304u;
  unsigned short* vb  = ws + 8388608u;
  unsigned short* wqb = ws + 12582912u;
  unsigned short* wkb = ws + 13631488u;
  unsigned short* wvb = ws + 14680064u;
  unsigned short* wob = ws + 15728640u;
  unsigned short* Qp  = ws + 16777216u;
  unsigned short* Kp  = ws + 20971520u;
  unsigned short* Vt  = ws + 25165824u;     // V^T [1024][4096]
  unsigned short* ctx = qb;                 // safe reuse: qb consumed by proj_qkv before attn
  float* out = (float*)d_out;

  cast_all<<<dim3(1024, 7), 256, 0, stream>>>(q, k, v, wq, wk, wv, wo, ws);
  proj_qkv<<<dim3(32, 8, 3), 256, 0, stream>>>(qb, kb, vb, wqb, wkb, wvb, Qp, Kp, Vt, bq, bk, bv);
  attn_fused<<<dim3(512), 512, 0, stream>>>(Qp, Kp, Vt, ctx);
  proj_o<<<dim3(32, 8), 256, 0, stream>>>(ctx, wob, out, bo);
}